// Round 14
// baseline (273.110 us; speedup 1.0000x reference)
//
#include <hip/hip_runtime.h>
#include <hip/hip_bf16.h>
#include <math.h>

// Problem constants (fixed by the reference)
#define NT    10000      // total nodes (BL*N)
#define NE    120000     // edges
#define MP    10240      // NT padded to 80*128 (GEMM row tiles)

using h8     = __attribute__((ext_vector_type(8))) _Float16;
using h4     = __attribute__((ext_vector_type(4))) _Float16;
using f32x4  = __attribute__((ext_vector_type(4))) float;
using f32x16 = __attribute__((ext_vector_type(16))) float;

struct Args {
    const float* x;
    const int*   src;
    const int*   dst;
    const float* ew;
    const float* W[6];        // Wl0,Wr0,Wl1,Wr1,Wl2,Wr2 (fp32 [K][N])
    const float* bl[3];
    const float* br[3];
    const float* We[3];
    const float* att[3];
    const float* bias[3];
    _Float16* wt[6];          // transposed fp16 [N][K]
    _Float16* xf;             // x as fp16
    _Float16* xl;  _Float16* xr;
    _Float16* af;             // activations fp16
    float* out;
    int* rowptr; int* cntcur; int* csr_src; float* csr_w;
    int* order;               // nodes sorted by descending degree
};

// ---------------------------------------------------------------------------
// Pure-fp16 MFMA GEMM jobs (r30 32x32x16 form, kept — neutral vs 16x16x32,
// r13 showed GEMMs are staging/barrier-bound not MFMA-bound; fewer MFMA
// instructions leaves more issue slots for staging).
// 64x64 wave tile = 2x2 f32x16 fragments; BK=32 double-buffer (r28),
// 32 KB LDS, 4 blocks/CU, XCD-slab job swizzle.
// Layouts (guide-verified): A/B row|col=lane&31, k=(lane>>5)*8;
// C/D col=lane&31, row=(reg&3)+8*(reg>>2)+4*(lane>>5)  [m74/m101].
// ---------------------------------------------------------------------------
__device__ __forceinline__ void gemm_jobs(
    const _Float16* __restrict__ A,
    const _Float16* __restrict__ WlT, const _Float16* __restrict__ WrT,
    const float* __restrict__ biasl, const float* __restrict__ biasr,
    _Float16* __restrict__ outl, _Float16* __restrict__ outr,
    int M, int N, int K, int njobs, int job0, int jstep, _Float16* sm)
{
    int tid = threadIdx.x;
    int wave = tid >> 6, lane = tid & 63;
    int l31 = lane & 31;
    int lk8 = (lane >> 5) * 8;
    int wm = (wave & 1) << 6;
    int wn = (wave >> 1) << 6;

    for (int job = job0; job < njobs; job += jstep) {
        int xcd = job & 7;
        int kk  = job >> 3;
        int r   = kk % 10;
        int byy = kk / 10;
        int bm  = (xcd * 10 + r) * 128;

        int nby = N >> 7;
        bool isR = byy >= nby;
        int bnn = (isR ? byy - nby : byy) << 7;
        const _Float16* Bh = isR ? WrT : WlT;
        const float* bias  = isR ? biasr : biasl;
        _Float16* out      = isR ? outr : outl;

        f32x16 acc[2][2] = {};

        // stage a 128x32 A tile + 128x32 B tile (16 chunks of 32rows x 16k)
        auto stage = [&](int b, int k0) {
            #pragma unroll
            for (int q = 0; q < 4; ++q) {
                int p = wave * 4 + q;          // 0..15
                int bufi = p >> 3;             // 0:A 1:B
                int c = p & 7;                 // chunk
                int rg2 = c & 3, ks = c >> 2;
                const _Float16* g = (bufi == 0) ? A : Bh;
                int rowbase = (bufi == 0) ? bm : bnn;
                _Float16* sb = sm + b * 8192 + bufi * 4096 + c * 512;
                const _Float16* gp = g + (size_t)(rowbase + rg2 * 32 + l31) * K
                                       + k0 + ks * 16 + lk8;
                __builtin_amdgcn_global_load_lds(
                    (const __attribute__((address_space(1))) void*)gp,
                    (__attribute__((address_space(3))) void*)sb,
                    16, 0, 0);
            }
        };

        int nt = K >> 5;                       // K/32 tiles
        stage(0, 0);                           // prologue
        for (int t = 0; t < nt; ++t) {
            __syncthreads();                   // drains staging of buf t&1
            if (t + 1 < nt) stage((t + 1) & 1, (t + 1) << 5);
            const _Float16* sA = sm + (t & 1) * 8192;
            const _Float16* sB = sA + 4096;
            #pragma unroll
            for (int ks = 0; ks < 2; ++ks) {
                h8 a0 = *(const h8*)(sA + (ks * 4 + (wave & 1) * 2 + 0) * 512 + lane * 8);
                h8 a1 = *(const h8*)(sA + (ks * 4 + (wave & 1) * 2 + 1) * 512 + lane * 8);
                h8 b0 = *(const h8*)(sB + (ks * 4 + (wave >> 1) * 2 + 0) * 512 + lane * 8);
                h8 b1 = *(const h8*)(sB + (ks * 4 + (wave >> 1) * 2 + 1) * 512 + lane * 8);
                acc[0][0] = __builtin_amdgcn_mfma_f32_32x32x16_f16(a0, b0, acc[0][0], 0, 0, 0);
                acc[0][1] = __builtin_amdgcn_mfma_f32_32x32x16_f16(a0, b1, acc[0][1], 0, 0, 0);
                acc[1][0] = __builtin_amdgcn_mfma_f32_32x32x16_f16(a1, b0, acc[1][0], 0, 0, 0);
                acc[1][1] = __builtin_amdgcn_mfma_f32_32x32x16_f16(a1, b1, acc[1][1], 0, 0, 0);
            }
        }

        // epilogue: C/D col=lane&31, row=(reg&3)+8*(reg>>2)+4*(lane>>5)
        #pragma unroll
        for (int j = 0; j < 2; ++j) {
            int col = bnn + wn + j * 32 + l31;
            float bv = bias[col];
            #pragma unroll
            for (int i = 0; i < 2; ++i) {
                int base_row = bm + wm + i * 32 + 4 * (lane >> 5);
                #pragma unroll
                for (int reg = 0; reg < 16; ++reg) {
                    int row = base_row + (reg & 3) + 8 * (reg >> 2);
                    if (row < M)
                        out[(size_t)row * N + col] = (_Float16)(acc[i][j][reg] + bv);
                }
            }
        }
    }
}

// ---------------------------------------------------------------------------
// prep + hist (r26 form, kept): one work item per block.
// Grid = 1457: [0,832) weight transpose tiles | [832,1457) x-convert items
// (float4 -> h4 vectorized, 1024 floats per item). Histogram grid-strided.
// scan fusion ABANDONED (r2/r8 both regressed).
// ---------------------------------------------------------------------------
__global__ void preph_k(Args a) {
    __shared__ float sf[32 * 33];
    const int mat_cum[7] = {0, 32, 64, 320, 576, 704, 832};
    const int mat_K[6]   = {64, 64, 512, 512, 512, 512};
    const int mat_N[6]   = {512, 512, 512, 512, 256, 256};
    int w = blockIdx.x;
    int tid = threadIdx.x;
    int tx = tid & 31, ty = tid >> 5;
    if (w < 832) {
        int t = w;
        int mm = 0;
        #pragma unroll
        for (int q = 1; q < 6; ++q) if (t >= mat_cum[q]) mm = q;
        int tt = t - mat_cum[mm];
        int K = mat_K[mm], N = mat_N[mm];
        int tiles_k = K >> 5;
        int tk = tt % tiles_k, tn = tt / tiles_k;
        const float* W = a.W[mm];
        _Float16* T = a.wt[mm];
        int bk = tk * 32, bn = tn * 32;
        #pragma unroll
        for (int i = 0; i < 4; ++i)
            sf[(ty * 4 + i) * 33 + tx] =
                W[(size_t)(bk + ty * 4 + i) * N + bn + tx];
        __syncthreads();
        #pragma unroll
        for (int i = 0; i < 4; ++i) {
            int nn = ty * 4 + i;
            T[(size_t)(bn + nn) * K + bk + tx] = (_Float16)sf[tx * 33 + nn];
        }
    } else {
        // x convert: item covers 1024 floats; 625 items cover NT*64 exactly
        int i = (w - 832) * 1024 + tid * 4;
        float4 v = *(const float4*)(a.x + i);
        h4 o;
        o[0] = (_Float16)v.x; o[1] = (_Float16)v.y;
        o[2] = (_Float16)v.z; o[3] = (_Float16)v.w;
        *(h4*)(a.xf + i) = o;
    }
    // histogram (cnt zeroed by the preceding memset); <=1 iter at grid 1457
    for (int e = w * 256 + tid; e < NE; e += 1457 * 256)
        atomicAdd(&a.cntcur[a.dst[e]], 1);
}

// ---------------------------------------------------------------------------
// scan + degree-sort (r29, kept: -8.5 µs): exclusive prefix over cnt ->
// rowptr, PLUS 256-bin counting sort of nodes by DESCENDING degree ->
// order[] (LPT scheduling + homogeneous blocks for edge_k).
// ---------------------------------------------------------------------------
__global__ __launch_bounds__(1024) void scan_k(Args a) {
    __shared__ int si[1024];
    __shared__ int bins[256];
    int tid = threadIdx.x;
    const int PER = 10;   // 1024*10 = 10240 >= NT+1
    int base = tid * PER;
    int cntv[PER];
    int s = 0;
    for (int i = 0; i < PER; ++i) {
        int idx = base + i;
        cntv[i] = (idx < NT) ? a.cntcur[idx] : 0;
        s += cntv[i];
    }
    si[tid] = s;
    if (tid < 256) bins[tid] = 0;
    __syncthreads();
    for (int off = 1; off < 1024; off <<= 1) {
        int v = (tid >= off) ? si[tid - off] : 0;
        __syncthreads();
        si[tid] += v;
        __syncthreads();
    }
    int run = (tid == 0) ? 0 : si[tid - 1];
    for (int i = 0; i < PER; ++i) {
        int idx = base + i;
        if (idx < NT) { a.rowptr[idx] = run; run += cntv[i]; }
        else if (idx == NT) a.rowptr[idx] = run;
    }
    // degree histogram (clamped to 255)
    for (int i = 0; i < PER; ++i) {
        int idx = base + i;
        if (idx < NT) {
            int d = cntv[i] > 255 ? 255 : cntv[i];
            atomicAdd(&bins[d], 1);
        }
    }
    __syncthreads();
    // descending start offsets: bins[d] <- sum of counts of degrees > d
    if (tid == 0) {
        int acc = 0;
        for (int d = 255; d >= 0; --d) {
            int c = bins[d];
            bins[d] = acc;
            acc += c;
        }
    }
    __syncthreads();
    // scatter node ids into order[] (bins[] doubles as cursor)
    for (int i = 0; i < PER; ++i) {
        int idx = base + i;
        if (idx < NT) {
            int d = cntv[i] > 255 ? 255 : cntv[i];
            int pos = atomicAdd(&bins[d], 1);
            a.order[pos] = idx;
        }
    }
}

// ---------------------------------------------------------------------------
// scatter + GEMM L0 FUSED: blocks [0,160) scatter edges into CSR;
// blocks [160,800) run the 640 GEMM-L0 jobs. Scatter hides under GEMM L0.
// ---------------------------------------------------------------------------
__global__ __launch_bounds__(256, 4) void scatgemm_k(Args a) {
    __shared__ __align__(16) _Float16 sm[2 * 8192];   // 32 KB
    int b = blockIdx.x;
    if (b < 160) {
        int* cursor = a.cntcur + NT;
        for (int e = b * 256 + (int)threadIdx.x; e < NE; e += 160 * 256) {
            int d = a.dst[e];
            int pos = atomicAdd(&cursor[d], 1);
            int idx = a.rowptr[d] + pos;
            a.csr_src[idx] = a.src[e];
            a.csr_w[idx]  = a.ew[e];
        }
    } else {
        gemm_jobs(a.xf, a.wt[0], a.wt[1], a.bl[0], a.br[0],
                  a.xl, a.xr, NT, 512, 64, 640, b - 160, 640, sm);
    }
}

// ---------------------------------------------------------------------------
// standalone GEMM (layers 1, 2)
// ---------------------------------------------------------------------------
__global__ __launch_bounds__(256, 4) void gemm_k(
    const _Float16* A, const _Float16* WlT, const _Float16* WrT,
    const float* bl, const float* br,
    _Float16* ol, _Float16* orr, int M, int N, int K, int njobs) {
    __shared__ __align__(16) _Float16 sm[2 * 8192];
    gemm_jobs(A, WlT, WrT, bl, br, ol, orr, M, N, K, njobs,
              blockIdx.x, gridDim.x, sm);
}

// ---------------------------------------------------------------------------
// Fused edge attention: online softmax, chunked index broadcast + depth-4
// row-gather pipeline (r6/r9 step form) + degree-sorted node order (r29).
// r31 (this round): exact skip-rescale, retested ISOLATED (r3's test was
// confounded with depth-6 VGPR pressure). When __all(part <= m) the rescale
// factor is exactly 1.0 -> skip one exp (quarter-rate) + the m update and
// use the shorter av += p*xlv chain. Wave-uniform branch; ~+2 VGPR, no
// arrays, no cap -> no spill/tier risk. Degree-sorted blocks make the
// branch coherent across the wave's lifetime.
// History: depth-6+skip (r3), (256,8) cap (r4, spill), depth-5 (r7),
// WPN=2 (r10) all REVERTED. NEVER hard-cap VGPR here.
// ---------------------------------------------------------------------------
template<int C, int H, bool DO_ELU, bool FP16OUT>
__global__ __launch_bounds__(256) void edge_k(
    const _Float16* __restrict__ xl, const _Float16* __restrict__ xr,
    const int* __restrict__ rowptr, const int* __restrict__ csr_src,
    const float* __restrict__ csr_w,
    const int* __restrict__ order,
    const float* __restrict__ We, const float* __restrict__ att,
    const float* __restrict__ bias,
    float* __restrict__ outf, _Float16* __restrict__ outh)
{
    constexpr int CHT = C * H;        // flat channels per node
    constexpr int VPT = CHT / 64;     // channels per lane
    constexpr int G   = 64 / H;       // lanes per head group

    int gw = (blockIdx.x * 256 + (int)threadIdx.x) >> 6;
    int lane = threadIdx.x & 63;
    if (gw >= NT) return;
    int node = order[gw];             // degree-descending permutation
    int c0 = lane * VPT;
    size_t nbase = (size_t)node * CHT + c0;

    float xr_reg[VPT], we_reg[VPT], att_reg[VPT];
    {
        _Float16 t[VPT];
        if (VPT == 8) *(h8*)t = *(const h8*)(xr + nbase);
        else          *(h4*)t = *(const h4*)(xr + nbase);
        #pragma unroll
        for (int v = 0; v < VPT; ++v) xr_reg[v] = (float)t[v];
    }
    #pragma unroll
    for (int v = 0; v < VPT; v += 4) {
        *(float4*)(we_reg + v)   = *(const float4*)(We + c0 + v);
        *(float4*)(att_reg + v)  = *(const float4*)(att + c0 + v);
    }

    int rs = rowptr[node];
    int re = rowptr[node + 1];

    float m = -INFINITY, ssum = 0.f;
    float av[VPT];
    #pragma unroll
    for (int v = 0; v < VPT; ++v) av[v] = 0.f;

    for (int base = rs; base < re; base += 64) {
        int cn = re - base;
        if (cn > 64) cn = 64;
        int le = base + lane;
        int cl = (le < re) ? le : (re - 1);
        int   sidx = csr_src[cl];
        float swt  = csr_w[cl];

        _Float16 r0[VPT], r1[VPT], r2[VPT], r3[VPT];
        auto ld = [&](int j, _Float16* dst) {
            int s = __shfl(sidx, j, 64);
            const _Float16* p = xl + (size_t)s * CHT + c0;
            if (VPT == 8) *(h8*)dst = *(const h8*)p;
            else          *(h4*)dst = *(const h4*)p;
        };
        auto step = [&](const _Float16* rc, int j) {
            float w = __shfl(swt, j, 64);
            float part = 0.f;
            #pragma unroll
            for (int v = 0; v < VPT; ++v) {
                float t = fmaf(w, we_reg[v], xr_reg[v]) + (float)rc[v];
                t = fmaxf(t, 0.2f * t);           // leaky-relu, slope<1
                part += t * att_reg[v];
            }
            #pragma unroll
            for (int off = G / 2; off > 0; off >>= 1)
                part += __shfl_xor(part, off, 64);
            if (__all(part <= m)) {
                // max unchanged in every head group: fac == 1.0 exactly
                float p = __expf(part - m);
                ssum += p;
                #pragma unroll
                for (int v = 0; v < VPT; ++v)
                    av[v] = fmaf(p, (float)rc[v], av[v]);
            } else {
                float newm = fmaxf(m, part);
                float fac = __expf(m - newm);
                float p = __expf(part - newm);
                ssum = ssum * fac + p;
                #pragma unroll
                for (int v = 0; v < VPT; ++v)
                    av[v] = fmaf(av[v], fac, p * (float)rc[v]);
                m = newm;
            }
        };

        ld(0, r0);
        if (cn > 1) ld(1, r1);
        if (cn > 2) ld(2, r2);
        if (cn > 3) ld(3, r3);

        int j = 0;
        while (j < cn) {
            step(r0, j);
            if (j + 4 < cn) ld(j + 4, r0);
            if (++j >= cn) break;
            step(r1, j);
            if (j + 4 < cn) ld(j + 4, r1);
            if (++j >= cn) break;
            step(r2, j);
            if (j + 4 < cn) ld(j + 4, r2);
            if (++j >= cn) break;
            step(r3, j);
            if (j + 4 < cn) ld(j + 4, r3);
            ++j;
        }
    }

    float inv = 1.f / (ssum + 1e-16f);
    #pragma unroll
    for (int v = 0; v < VPT; ++v) {
        float o = av[v] * inv + bias[c0 + v];   // bias loaded here (epilogue)
        if (DO_ELU) o = (o > 0.f) ? o : (__expf(o) - 1.f);
        if (FP16OUT) outh[nbase + v] = (_Float16)o;
        else         outf[nbase + v] = o;
    }
}

// ---------------------------------------------------------------------------
extern "C" void kernel_launch(void* const* d_in, const int* in_sizes, int n_in,
                              void* d_out, int out_size, void* d_ws, size_t ws_size,
                              hipStream_t stream) {
    Args a;
    a.x   = (const float*)d_in[0];
    const int* ei = (const int*)d_in[1];
    a.src = ei;
    a.dst = ei + NE;
    a.ew  = (const float*)d_in[2];
    for (int l = 0; l < 3; ++l) {
        int base = 3 + 7 * l;
        a.W[2 * l]     = (const float*)d_in[base + 0];   // Wl
        a.bl[l]        = (const float*)d_in[base + 1];
        a.W[2 * l + 1] = (const float*)d_in[base + 2];   // Wr
        a.br[l]        = (const float*)d_in[base + 3];
        a.We[l]        = (const float*)d_in[base + 4];
        a.att[l]       = (const float*)d_in[base + 5];
        a.bias[l]      = (const float*)d_in[base + 6];
    }

    size_t off = 0;
    auto alloc = [&](size_t bytes) -> void* {
        void* p = (char*)d_ws + off;
        off += (bytes + 255) & ~(size_t)255;
        return p;
    };
    a.xl   = (_Float16*)alloc((size_t)MP * 512 * 2);
    a.xr   = (_Float16*)alloc((size_t)MP * 512 * 2);
    a.af   = (_Float16*)alloc((size_t)MP * 512 * 2);
    a.xf   = (_Float16*)alloc((size_t)MP * 64 * 2);
    const int KD[3] = {64, 512, 512};
    const int ND[3] = {512, 512, 256};
    for (int l = 0; l < 3; ++l) {
        a.wt[2 * l]     = (_Float16*)alloc((size_t)KD[l] * ND[l] * 2);
        a.wt[2 * l + 1] = (_Float16*)alloc((size_t)KD[l] * ND[l] * 2);
    }
    a.rowptr  = (int*)alloc((size_t)(NT + 1) * 4);
    a.cntcur  = (int*)alloc((size_t)2 * NT * 4);
    a.csr_src = (int*)alloc((size_t)NE * 4);
    a.csr_w   = (float*)alloc((size_t)NE * 4);
    a.order   = (int*)alloc((size_t)NT * 4);
    a.out     = (float*)d_out;

    hipMemsetAsync(a.cntcur, 0, (size_t)2 * NT * 4, stream);
    preph_k<<<1457, 256, 0, stream>>>(a);
    scan_k<<<1, 1024, 0, stream>>>(a);
    scatgemm_k<<<800, 256, 0, stream>>>(a);   // scatter || GEMM L0

    // Layer 0 edge (degree-sorted order)
    edge_k<128, 4, true, true><<<2500, 256, 0, stream>>>(
        a.xl, a.xr, a.rowptr, a.csr_src, a.csr_w, a.order,
        a.We[0], a.att[0], a.bias[0], nullptr, a.af);

    // Layer 1: K=512, N=512/side
    gemm_k<<<640, 256, 0, stream>>>(a.af, a.wt[2], a.wt[3],
                                    a.bl[1], a.br[1], a.xl, a.xr,
                                    NT, 512, 512, 640);
    edge_k<128, 4, true, true><<<2500, 256, 0, stream>>>(
        a.xl, a.xr, a.rowptr, a.csr_src, a.csr_w, a.order,
        a.We[1], a.att[1], a.bias[1], nullptr, a.af);

    // Layer 2: K=512, N=256/side
    gemm_k<<<320, 256, 0, stream>>>(a.af, a.wt[4], a.wt[5],
                                    a.bl[2], a.br[2], a.xl, a.xr,
                                    NT, 256, 512, 320);
    edge_k<256, 1, false, false><<<2500, 256, 0, stream>>>(
        a.xl, a.xr, a.rowptr, a.csr_src, a.csr_w, a.order,
        a.We[2], a.att[2], a.bias[2], a.out, nullptr);
}

// Round 15
// 268.251 us; speedup vs baseline: 1.0181x; 1.0181x over previous
//
#include <hip/hip_runtime.h>
#include <hip/hip_bf16.h>
#include <math.h>

// Problem constants (fixed by the reference)
#define NT    10000      // total nodes (BL*N)
#define NE    120000     // edges
#define MP    10240      // NT padded to 80*128 (GEMM row tiles)

using h8     = __attribute__((ext_vector_type(8))) _Float16;
using h4     = __attribute__((ext_vector_type(4))) _Float16;
using f32x4  = __attribute__((ext_vector_type(4))) float;
using f32x16 = __attribute__((ext_vector_type(16))) float;

struct Args {
    const float* x;
    const int*   src;
    const int*   dst;
    const float* ew;
    const float* W[6];        // Wl0,Wr0,Wl1,Wr1,Wl2,Wr2 (fp32 [K][N])
    const float* bl[3];
    const float* br[3];
    const float* We[3];
    const float* att[3];
    const float* bias[3];
    _Float16* wt[6];          // transposed fp16 [N][K]
    _Float16* xf;             // x as fp16
    _Float16* xl;  _Float16* xr;
    _Float16* af;             // activations fp16
    float* out;
    int* rowptr; int* cntcur; int* csr_src; float* csr_w;
    int* order;               // nodes sorted by descending degree
};

// ---------------------------------------------------------------------------
// Pure-fp16 MFMA GEMM jobs (r30 32x32x16 form, kept — neutral vs 16x16x32,
// r13 showed GEMMs are staging/barrier-bound not MFMA-bound).
// 64x64 wave tile = 2x2 f32x16 fragments; BK=32 double-buffer (r28),
// 32 KB LDS, 4 blocks/CU, XCD-slab job swizzle.
// Layouts (guide-verified): A/B row|col=lane&31, k=(lane>>5)*8;
// C/D col=lane&31, row=(reg&3)+8*(reg>>2)+4*(lane>>5)  [m74/m101].
// ---------------------------------------------------------------------------
__device__ __forceinline__ void gemm_jobs(
    const _Float16* __restrict__ A,
    const _Float16* __restrict__ WlT, const _Float16* __restrict__ WrT,
    const float* __restrict__ biasl, const float* __restrict__ biasr,
    _Float16* __restrict__ outl, _Float16* __restrict__ outr,
    int M, int N, int K, int njobs, int job0, int jstep, _Float16* sm)
{
    int tid = threadIdx.x;
    int wave = tid >> 6, lane = tid & 63;
    int l31 = lane & 31;
    int lk8 = (lane >> 5) * 8;
    int wm = (wave & 1) << 6;
    int wn = (wave >> 1) << 6;

    for (int job = job0; job < njobs; job += jstep) {
        int xcd = job & 7;
        int kk  = job >> 3;
        int r   = kk % 10;
        int byy = kk / 10;
        int bm  = (xcd * 10 + r) * 128;

        int nby = N >> 7;
        bool isR = byy >= nby;
        int bnn = (isR ? byy - nby : byy) << 7;
        const _Float16* Bh = isR ? WrT : WlT;
        const float* bias  = isR ? biasr : biasl;
        _Float16* out      = isR ? outr : outl;

        f32x16 acc[2][2] = {};

        // stage a 128x32 A tile + 128x32 B tile (16 chunks of 32rows x 16k)
        auto stage = [&](int b, int k0) {
            #pragma unroll
            for (int q = 0; q < 4; ++q) {
                int p = wave * 4 + q;          // 0..15
                int bufi = p >> 3;             // 0:A 1:B
                int c = p & 7;                 // chunk
                int rg2 = c & 3, ks = c >> 2;
                const _Float16* g = (bufi == 0) ? A : Bh;
                int rowbase = (bufi == 0) ? bm : bnn;
                _Float16* sb = sm + b * 8192 + bufi * 4096 + c * 512;
                const _Float16* gp = g + (size_t)(rowbase + rg2 * 32 + l31) * K
                                       + k0 + ks * 16 + lk8;
                __builtin_amdgcn_global_load_lds(
                    (const __attribute__((address_space(1))) void*)gp,
                    (__attribute__((address_space(3))) void*)sb,
                    16, 0, 0);
            }
        };

        int nt = K >> 5;                       // K/32 tiles
        stage(0, 0);                           // prologue
        for (int t = 0; t < nt; ++t) {
            __syncthreads();                   // drains staging of buf t&1
            if (t + 1 < nt) stage((t + 1) & 1, (t + 1) << 5);
            const _Float16* sA = sm + (t & 1) * 8192;
            const _Float16* sB = sA + 4096;
            #pragma unroll
            for (int ks = 0; ks < 2; ++ks) {
                h8 a0 = *(const h8*)(sA + (ks * 4 + (wave & 1) * 2 + 0) * 512 + lane * 8);
                h8 a1 = *(const h8*)(sA + (ks * 4 + (wave & 1) * 2 + 1) * 512 + lane * 8);
                h8 b0 = *(const h8*)(sB + (ks * 4 + (wave >> 1) * 2 + 0) * 512 + lane * 8);
                h8 b1 = *(const h8*)(sB + (ks * 4 + (wave >> 1) * 2 + 1) * 512 + lane * 8);
                acc[0][0] = __builtin_amdgcn_mfma_f32_32x32x16_f16(a0, b0, acc[0][0], 0, 0, 0);
                acc[0][1] = __builtin_amdgcn_mfma_f32_32x32x16_f16(a0, b1, acc[0][1], 0, 0, 0);
                acc[1][0] = __builtin_amdgcn_mfma_f32_32x32x16_f16(a1, b0, acc[1][0], 0, 0, 0);
                acc[1][1] = __builtin_amdgcn_mfma_f32_32x32x16_f16(a1, b1, acc[1][1], 0, 0, 0);
            }
        }

        // epilogue: C/D col=lane&31, row=(reg&3)+8*(reg>>2)+4*(lane>>5)
        #pragma unroll
        for (int j = 0; j < 2; ++j) {
            int col = bnn + wn + j * 32 + l31;
            float bv = bias[col];
            #pragma unroll
            for (int i = 0; i < 2; ++i) {
                int base_row = bm + wm + i * 32 + 4 * (lane >> 5);
                #pragma unroll
                for (int reg = 0; reg < 16; ++reg) {
                    int row = base_row + (reg & 3) + 8 * (reg >> 2);
                    if (row < M)
                        out[(size_t)row * N + col] = (_Float16)(acc[i][j][reg] + bv);
                }
            }
        }
    }
}

// ---------------------------------------------------------------------------
// prep + hist (r26 form, kept): one work item per block.
// Grid = 1457: [0,832) weight transpose tiles | [832,1457) x-convert items
// (float4 -> h4 vectorized, 1024 floats per item). Histogram grid-strided.
// scan fusion ABANDONED (r2/r8 both regressed).
// ---------------------------------------------------------------------------
__global__ void preph_k(Args a) {
    __shared__ float sf[32 * 33];
    const int mat_cum[7] = {0, 32, 64, 320, 576, 704, 832};
    const int mat_K[6]   = {64, 64, 512, 512, 512, 512};
    const int mat_N[6]   = {512, 512, 512, 512, 256, 256};
    int w = blockIdx.x;
    int tid = threadIdx.x;
    int tx = tid & 31, ty = tid >> 5;
    if (w < 832) {
        int t = w;
        int mm = 0;
        #pragma unroll
        for (int q = 1; q < 6; ++q) if (t >= mat_cum[q]) mm = q;
        int tt = t - mat_cum[mm];
        int K = mat_K[mm], N = mat_N[mm];
        int tiles_k = K >> 5;
        int tk = tt % tiles_k, tn = tt / tiles_k;
        const float* W = a.W[mm];
        _Float16* T = a.wt[mm];
        int bk = tk * 32, bn = tn * 32;
        #pragma unroll
        for (int i = 0; i < 4; ++i)
            sf[(ty * 4 + i) * 33 + tx] =
                W[(size_t)(bk + ty * 4 + i) * N + bn + tx];
        __syncthreads();
        #pragma unroll
        for (int i = 0; i < 4; ++i) {
            int nn = ty * 4 + i;
            T[(size_t)(bn + nn) * K + bk + tx] = (_Float16)sf[tx * 33 + nn];
        }
    } else {
        // x convert: item covers 1024 floats; 625 items cover NT*64 exactly
        int i = (w - 832) * 1024 + tid * 4;
        float4 v = *(const float4*)(a.x + i);
        h4 o;
        o[0] = (_Float16)v.x; o[1] = (_Float16)v.y;
        o[2] = (_Float16)v.z; o[3] = (_Float16)v.w;
        *(h4*)(a.xf + i) = o;
    }
    // histogram (cnt zeroed by the preceding memset); <=1 iter at grid 1457
    for (int e = w * 256 + tid; e < NE; e += 1457 * 256)
        atomicAdd(&a.cntcur[a.dst[e]], 1);
}

// ---------------------------------------------------------------------------
// scan + degree-sort (r29, kept: -8.5 µs): exclusive prefix over cnt ->
// rowptr, PLUS 256-bin counting sort of nodes by DESCENDING degree ->
// order[] (LPT scheduling + homogeneous blocks for edge_k).
// ---------------------------------------------------------------------------
__global__ __launch_bounds__(1024) void scan_k(Args a) {
    __shared__ int si[1024];
    __shared__ int bins[256];
    int tid = threadIdx.x;
    const int PER = 10;   // 1024*10 = 10240 >= NT+1
    int base = tid * PER;
    int cntv[PER];
    int s = 0;
    for (int i = 0; i < PER; ++i) {
        int idx = base + i;
        cntv[i] = (idx < NT) ? a.cntcur[idx] : 0;
        s += cntv[i];
    }
    si[tid] = s;
    if (tid < 256) bins[tid] = 0;
    __syncthreads();
    for (int off = 1; off < 1024; off <<= 1) {
        int v = (tid >= off) ? si[tid - off] : 0;
        __syncthreads();
        si[tid] += v;
        __syncthreads();
    }
    int run = (tid == 0) ? 0 : si[tid - 1];
    for (int i = 0; i < PER; ++i) {
        int idx = base + i;
        if (idx < NT) { a.rowptr[idx] = run; run += cntv[i]; }
        else if (idx == NT) a.rowptr[idx] = run;
    }
    // degree histogram (clamped to 255)
    for (int i = 0; i < PER; ++i) {
        int idx = base + i;
        if (idx < NT) {
            int d = cntv[i] > 255 ? 255 : cntv[i];
            atomicAdd(&bins[d], 1);
        }
    }
    __syncthreads();
    // descending start offsets: bins[d] <- sum of counts of degrees > d
    if (tid == 0) {
        int acc = 0;
        for (int d = 255; d >= 0; --d) {
            int c = bins[d];
            bins[d] = acc;
            acc += c;
        }
    }
    __syncthreads();
    // scatter node ids into order[] (bins[] doubles as cursor)
    for (int i = 0; i < PER; ++i) {
        int idx = base + i;
        if (idx < NT) {
            int d = cntv[i] > 255 ? 255 : cntv[i];
            int pos = atomicAdd(&bins[d], 1);
            a.order[pos] = idx;
        }
    }
}

// ---------------------------------------------------------------------------
// scatter + GEMM L0 FUSED: blocks [0,160) scatter edges into CSR;
// blocks [160,800) run the 640 GEMM-L0 jobs. Scatter hides under GEMM L0.
// ---------------------------------------------------------------------------
__global__ __launch_bounds__(256, 4) void scatgemm_k(Args a) {
    __shared__ __align__(16) _Float16 sm[2 * 8192];   // 32 KB
    int b = blockIdx.x;
    if (b < 160) {
        int* cursor = a.cntcur + NT;
        for (int e = b * 256 + (int)threadIdx.x; e < NE; e += 160 * 256) {
            int d = a.dst[e];
            int pos = atomicAdd(&cursor[d], 1);
            int idx = a.rowptr[d] + pos;
            a.csr_src[idx] = a.src[e];
            a.csr_w[idx]  = a.ew[e];
        }
    } else {
        gemm_jobs(a.xf, a.wt[0], a.wt[1], a.bl[0], a.br[0],
                  a.xl, a.xr, NT, 512, 64, 640, b - 160, 640, sm);
    }
}

// ---------------------------------------------------------------------------
// standalone GEMM (layers 1, 2)
// ---------------------------------------------------------------------------
__global__ __launch_bounds__(256, 4) void gemm_k(
    const _Float16* A, const _Float16* WlT, const _Float16* WrT,
    const float* bl, const float* br,
    _Float16* ol, _Float16* orr, int M, int N, int K, int njobs) {
    __shared__ __align__(16) _Float16 sm[2 * 8192];
    gemm_jobs(A, WlT, WrT, bl, br, ol, orr, M, N, K, njobs,
              blockIdx.x, gridDim.x, sm);
}

// ---------------------------------------------------------------------------
// Fused edge attention: online softmax, chunked index broadcast + depth-4
// row-gather pipeline (r6/r9 step form) + degree-sorted node order (r29).
// r32: skip-rescale (r14, +3.5 µs isolated) REVERTED — twice-refuted
// (r3 confounded, r14 isolated): branch cost > saved exp in this
// latency-bound kernel. This is the r12/r13-proven step body.
// History: depth-6+skip (r3), (256,8) cap (r4, spill), depth-5 (r7),
// WPN=2 (r10), skip-rescale (r14) all REVERTED. NEVER hard-cap VGPR.
// ---------------------------------------------------------------------------
template<int C, int H, bool DO_ELU, bool FP16OUT>
__global__ __launch_bounds__(256) void edge_k(
    const _Float16* __restrict__ xl, const _Float16* __restrict__ xr,
    const int* __restrict__ rowptr, const int* __restrict__ csr_src,
    const float* __restrict__ csr_w,
    const int* __restrict__ order,
    const float* __restrict__ We, const float* __restrict__ att,
    const float* __restrict__ bias,
    float* __restrict__ outf, _Float16* __restrict__ outh)
{
    constexpr int CHT = C * H;        // flat channels per node
    constexpr int VPT = CHT / 64;     // channels per lane
    constexpr int G   = 64 / H;       // lanes per head group

    int gw = (blockIdx.x * 256 + (int)threadIdx.x) >> 6;
    int lane = threadIdx.x & 63;
    if (gw >= NT) return;
    int node = order[gw];             // degree-descending permutation
    int c0 = lane * VPT;
    size_t nbase = (size_t)node * CHT + c0;

    float xr_reg[VPT], we_reg[VPT], att_reg[VPT];
    {
        _Float16 t[VPT];
        if (VPT == 8) *(h8*)t = *(const h8*)(xr + nbase);
        else          *(h4*)t = *(const h4*)(xr + nbase);
        #pragma unroll
        for (int v = 0; v < VPT; ++v) xr_reg[v] = (float)t[v];
    }
    #pragma unroll
    for (int v = 0; v < VPT; v += 4) {
        *(float4*)(we_reg + v)   = *(const float4*)(We + c0 + v);
        *(float4*)(att_reg + v)  = *(const float4*)(att + c0 + v);
    }

    int rs = rowptr[node];
    int re = rowptr[node + 1];

    float m = -INFINITY, ssum = 0.f;
    float av[VPT];
    #pragma unroll
    for (int v = 0; v < VPT; ++v) av[v] = 0.f;

    for (int base = rs; base < re; base += 64) {
        int cn = re - base;
        if (cn > 64) cn = 64;
        int le = base + lane;
        int cl = (le < re) ? le : (re - 1);
        int   sidx = csr_src[cl];
        float swt  = csr_w[cl];

        _Float16 r0[VPT], r1[VPT], r2[VPT], r3[VPT];
        auto ld = [&](int j, _Float16* dst) {
            int s = __shfl(sidx, j, 64);
            const _Float16* p = xl + (size_t)s * CHT + c0;
            if (VPT == 8) *(h8*)dst = *(const h8*)p;
            else          *(h4*)dst = *(const h4*)p;
        };
        auto step = [&](const _Float16* rc, int j) {
            float w = __shfl(swt, j, 64);
            float part = 0.f;
            #pragma unroll
            for (int v = 0; v < VPT; ++v) {
                float t = fmaf(w, we_reg[v], xr_reg[v]) + (float)rc[v];
                t = fmaxf(t, 0.2f * t);           // leaky-relu, slope<1
                part += t * att_reg[v];
            }
            #pragma unroll
            for (int off = G / 2; off > 0; off >>= 1)
                part += __shfl_xor(part, off, 64);
            float newm = fmaxf(m, part);
            float fac = __expf(m - newm);
            float p = __expf(part - newm);
            ssum = ssum * fac + p;
            #pragma unroll
            for (int v = 0; v < VPT; ++v)
                av[v] = fmaf(av[v], fac, p * (float)rc[v]);
            m = newm;
        };

        ld(0, r0);
        if (cn > 1) ld(1, r1);
        if (cn > 2) ld(2, r2);
        if (cn > 3) ld(3, r3);

        int j = 0;
        while (j < cn) {
            step(r0, j);
            if (j + 4 < cn) ld(j + 4, r0);
            if (++j >= cn) break;
            step(r1, j);
            if (j + 4 < cn) ld(j + 4, r1);
            if (++j >= cn) break;
            step(r2, j);
            if (j + 4 < cn) ld(j + 4, r2);
            if (++j >= cn) break;
            step(r3, j);
            if (j + 4 < cn) ld(j + 4, r3);
            ++j;
        }
    }

    float inv = 1.f / (ssum + 1e-16f);
    #pragma unroll
    for (int v = 0; v < VPT; ++v) {
        float o = av[v] * inv + bias[c0 + v];   // bias loaded here (epilogue)
        if (DO_ELU) o = (o > 0.f) ? o : (__expf(o) - 1.f);
        if (FP16OUT) outh[nbase + v] = (_Float16)o;
        else         outf[nbase + v] = o;
    }
}

// ---------------------------------------------------------------------------
extern "C" void kernel_launch(void* const* d_in, const int* in_sizes, int n_in,
                              void* d_out, int out_size, void* d_ws, size_t ws_size,
                              hipStream_t stream) {
    Args a;
    a.x   = (const float*)d_in[0];
    const int* ei = (const int*)d_in[1];
    a.src = ei;
    a.dst = ei + NE;
    a.ew  = (const float*)d_in[2];
    for (int l = 0; l < 3; ++l) {
        int base = 3 + 7 * l;
        a.W[2 * l]     = (const float*)d_in[base + 0];   // Wl
        a.bl[l]        = (const float*)d_in[base + 1];
        a.W[2 * l + 1] = (const float*)d_in[base + 2];   // Wr
        a.br[l]        = (const float*)d_in[base + 3];
        a.We[l]        = (const float*)d_in[base + 4];
        a.att[l]       = (const float*)d_in[base + 5];
        a.bias[l]      = (const float*)d_in[base + 6];
    }

    size_t off = 0;
    auto alloc = [&](size_t bytes) -> void* {
        void* p = (char*)d_ws + off;
        off += (bytes + 255) & ~(size_t)255;
        return p;
    };
    a.xl   = (_Float16*)alloc((size_t)MP * 512 * 2);
    a.xr   = (_Float16*)alloc((size_t)MP * 512 * 2);
    a.af   = (_Float16*)alloc((size_t)MP * 512 * 2);
    a.xf   = (_Float16*)alloc((size_t)MP * 64 * 2);
    const int KD[3] = {64, 512, 512};
    const int ND[3] = {512, 512, 256};
    for (int l = 0; l < 3; ++l) {
        a.wt[2 * l]     = (_Float16*)alloc((size_t)KD[l] * ND[l] * 2);
        a.wt[2 * l + 1] = (_Float16*)alloc((size_t)KD[l] * ND[l] * 2);
    }
    a.rowptr  = (int*)alloc((size_t)(NT + 1) * 4);
    a.cntcur  = (int*)alloc((size_t)2 * NT * 4);
    a.csr_src = (int*)alloc((size_t)NE * 4);
    a.csr_w   = (float*)alloc((size_t)NE * 4);
    a.order   = (int*)alloc((size_t)NT * 4);
    a.out     = (float*)d_out;

    hipMemsetAsync(a.cntcur, 0, (size_t)2 * NT * 4, stream);
    preph_k<<<1457, 256, 0, stream>>>(a);
    scan_k<<<1, 1024, 0, stream>>>(a);
    scatgemm_k<<<800, 256, 0, stream>>>(a);   // scatter || GEMM L0

    // Layer 0 edge (degree-sorted order)
    edge_k<128, 4, true, true><<<2500, 256, 0, stream>>>(
        a.xl, a.xr, a.rowptr, a.csr_src, a.csr_w, a.order,
        a.We[0], a.att[0], a.bias[0], nullptr, a.af);

    // Layer 1: K=512, N=512/side
    gemm_k<<<640, 256, 0, stream>>>(a.af, a.wt[2], a.wt[3],
                                    a.bl[1], a.br[1], a.xl, a.xr,
                                    NT, 512, 512, 640);
    edge_k<128, 4, true, true><<<2500, 256, 0, stream>>>(
        a.xl, a.xr, a.rowptr, a.csr_src, a.csr_w, a.order,
        a.We[1], a.att[1], a.bias[1], nullptr, a.af);

    // Layer 2: K=512, N=256/side
    gemm_k<<<320, 256, 0, stream>>>(a.af, a.wt[4], a.wt[5],
                                    a.bl[2], a.br[2], a.xl, a.xr,
                                    NT, 256, 512, 320);
    edge_k<256, 1, false, false><<<2500, 256, 0, stream>>>(
        a.xl, a.xr, a.rowptr, a.csr_src, a.csr_w, a.order,
        a.We[2], a.att[2], a.bias[2], a.out, nullptr);
}